// Round 5
// baseline (14.283 us; speedup 1.0000x reference)
//
#include <hip/hip_runtime.h>

// CCNOT(c1=0, c2=1, t=2) on 12 qubits, batch 2048.
// out[b, j] = state[b, j ^ (1<<9)] iff bits 11 and 10 of j are set, else state[b, j].
// Pure permuted copy. float4-index units: src_v = v ^ (1<<7) when column bits
// 11,10 set. Permutation is row-local and 2KiB-block aligned (coalesced).
//
// R5: software-pipelined interleave. Prime 4 loads, then alternate
// {store k, load k+4}, then drain stores 4..7. Spreads read/write traffic
// evenly over the kernel lifetime instead of a read-burst then write-burst,
// and shrinks the nt-store completion tail at endpgm.
// Keep: nt stores (R3 showed plain stores regress ~+1.4us).

#define DIM 4096

typedef float f32x4 __attribute__((ext_vector_type(4)));

__device__ __forceinline__ int src_of(int v) {
    int c = (v << 2) & (DIM - 1);               // element column within row
    int both = ((c >> 11) & (c >> 10)) & 1;     // controls: bits 11 & 10
    return v ^ (both << 7);                     // target flip: bit 7 in f4 units
}

__global__ __launch_bounds__(256) void ccnot_permute_kernel(
    const f32x4* __restrict__ in, f32x4* __restrict__ out) {
    const int base = blockIdx.x * 2048 + threadIdx.x;  // block covers 2048 f4 = 2 rows

    f32x4 vals[8];
    // prime: 4 loads in flight
#pragma unroll
    for (int k = 0; k < 4; ++k) vals[k] = in[src_of(base + k * 256)];
    // steady: store k, issue load k+4
#pragma unroll
    for (int k = 0; k < 4; ++k) {
        __builtin_nontemporal_store(vals[k], &out[base + k * 256]);
        vals[k + 4] = in[src_of(base + (k + 4) * 256)];
    }
    // drain
#pragma unroll
    for (int k = 4; k < 8; ++k) {
        __builtin_nontemporal_store(vals[k], &out[base + k * 256]);
    }
}

extern "C" void kernel_launch(void* const* d_in, const int* in_sizes, int n_in,
                              void* d_out, int out_size, void* d_ws, size_t ws_size,
                              hipStream_t stream) {
    const f32x4* state = (const f32x4*)d_in[0];
    f32x4* out = (f32x4*)d_out;
    dim3 block(256);
    dim3 grid(1024);  // 2 rows per block
    ccnot_permute_kernel<<<grid, block, 0, stream>>>(state, out);
}